// Round 9
// baseline (138.288 us; speedup 1.0000x reference)
//
#include <hip/hip_runtime.h>
#include <math.h>

#define B_   16
#define N_   256
#define F_   64
#define FP_  16
#define H_   128
#define K_   14                    // Chebyshev terms
#define M_   64                    // Gauss-Chebyshev fit nodes (exact for deg < 2*M-K)
#define DMAX 1.7320508075688772f   // sqrt(3): r in [0,1]^3
#define PI_F 3.14159265358979323846f
#define LROW 264                   // padded LDS row stride (h16) for 256-j rows

typedef _Float16 h16;
typedef __attribute__((ext_vector_type(2))) _Float16 h16x2;
typedef __attribute__((ext_vector_type(8))) _Float16 h16x8;
typedef __attribute__((ext_vector_type(4))) float    f32x4;

__device__ __forceinline__ float sp(float x) {
    // numerically stable softplus
    return fmaxf(x, 0.0f) + log1pf(expf(-fabsf(x)));
}

// ONE kernel: per-block redundant Chebyshev fit of the per-pair MLP, then
// f_bar = (sum_k c_k T_k(X)) @ fb via f16 MFMA, then pointwise MLP tail.
// grid = B_*(N_/16) = 256 blocks, 256 threads (4 waves x 64-j windows)
__global__ __launch_bounds__(256) void pp_fused(
        const float* __restrict__ r,     const float* __restrict__ fb,
        const float* __restrict__ mp_w1, const float* __restrict__ mp_b1,
        const float* __restrict__ mp_w2, const float* __restrict__ mp_b2,
        const float* __restrict__ pc_w1, const float* __restrict__ pc_b1,
        const float* __restrict__ pc_w2, const float* __restrict__ pc_b2,
        float* __restrict__ out) {
    const int tid = threadIdx.x;
    const int b   = blockIdx.x >> 4;
    const int i0  = (blockIdx.x & 15) << 4;

    // one aliased arena, phase-sequenced by barriers:
    __shared__ __align__(16) char s_big[F_ * LROW * 2];   // 33792 B
    __shared__ h16   s_x[16 * LROW];                      // 8448 B
    __shared__ float s_c[K_ * F_];                        // 3584 B
    __shared__ float s_ri[16 * 3];                        // 192 B

    h16*   s_fbT  = (h16*)s_big;               // [64][LROW]   staging phase
    float* s_hid  = (float*)s_big;             // [32][128]    prelude phase A
    float* s_red  = (float*)(s_big + 16384);   // [4][14][64]  prelude phase B
    float* s_part = (float*)s_big;             // [4][16*68]   C partials
    float* s_fbar = (float*)(s_big + 17408);   // [16][64]
    float* s_h2   = (float*)(s_big + 21504);   // [16][128]

    if (tid < 48) s_ri[tid] = r[((size_t)b * N_ + i0) * 3 + tid];

    // ================= prelude: Chebyshev coefficients c[k][f] =============
    // vals[m][f] = sp(MLP(d_m)) at M_ Chebyshev nodes; DCT over m.
    const int pf = tid & 63, mg = tid >> 6;
    float acc[K_];
    #pragma unroll
    for (int k = 0; k < K_; ++k) acc[k] = 0.0f;

    for (int ch = 0; ch < M_ / 32; ++ch) {
        if (ch > 0) __syncthreads();
        // hidden layer for 32 nodes: 4096 items
        #pragma unroll
        for (int e = 0; e < 16; ++e) {
            const int idx = e * 256 + tid;
            const int ml = idx >> 7, h = idx & 127;
            const float th = PI_F * ((float)(ch * 32 + ml) + 0.5f) / (float)M_;
            const float d  = (__cosf(th) + 1.0f) * 0.5f * DMAX;
            s_hid[ml * H_ + h] = sp(fmaf(d, mp_w1[h], mp_b1[h]));
        }
        __syncthreads();
        // layer 2 + DCT accumulate: thread (pf, mg) handles 8 nodes
        #pragma unroll
        for (int mm = 0; mm < 8; ++mm) {
            const int ml = mg * 8 + mm;
            const int m  = ch * 32 + ml;
            float z = mp_b2[pf];
            #pragma unroll 8
            for (int h = 0; h < H_; ++h)
                z = fmaf(s_hid[ml * H_ + h], mp_w2[h * F_ + pf], z);
            const float val = sp(z);
            const float cth = __cosf(PI_F * ((float)m + 0.5f) / (float)M_);
            float t0 = 1.0f, t1 = cth;
            acc[0] += val;
            acc[1] = fmaf(val, t1, acc[1]);
            #pragma unroll
            for (int k = 2; k < K_; ++k) {
                const float t2 = fmaf(2.0f * cth, t1, -t0);
                acc[k] = fmaf(val, t2, acc[k]);
                t0 = t1; t1 = t2;
            }
        }
    }
    __syncthreads();
    #pragma unroll
    for (int k = 0; k < K_; ++k)
        s_red[(mg * K_ + k) * F_ + pf] = acc[k];
    __syncthreads();
    #pragma unroll
    for (int p = 0; p < 4; ++p) {
        const int idx = p * 256 + tid;
        if (idx < K_ * F_) {
            const int k = idx >> 6, f = idx & 63;
            const float s = s_red[(0 * K_ + k) * F_ + f] + s_red[(1 * K_ + k) * F_ + f]
                          + s_red[(2 * K_ + k) * F_ + f] + s_red[(3 * K_ + k) * F_ + f];
            s_c[idx] = ((k == 0) ? 1.0f : 2.0f) * s / (float)M_;
        }
    }
    __syncthreads();   // s_red reads done; arena free for fbT

    // ================= stage fb^T (f32 -> f16) + x tile =====================
    {
        const float* fbb = fb + (size_t)b * N_ * F_;
        const int f4 = tid & 15;          // float4 group in f
        const int jp = tid >> 4;          // j-pair selector
        #pragma unroll
        for (int jb = 0; jb < 8; ++jb) {
            const int j0 = jb * 32 + jp * 2;
            const float4 v0 = *(const float4*)(fbb + (size_t)j0 * F_ + f4 * 4);
            const float4 v1 = *(const float4*)(fbb + (size_t)(j0 + 1) * F_ + f4 * 4);
            const float a0[4] = {v0.x, v0.y, v0.z, v0.w};
            const float a1[4] = {v1.x, v1.y, v1.z, v1.w};
            #pragma unroll
            for (int ff = 0; ff < 4; ++ff) {
                h16x2 pk; pk.x = (h16)a0[ff]; pk.y = (h16)a1[ff];
                *(h16x2*)&s_fbT[(f4 * 4 + ff) * LROW + j0] = pk;
            }
        }
    }
    {
        const int j = tid;
        const float xj = r[((size_t)b * N_ + j) * 3 + 0];
        const float yj = r[((size_t)b * N_ + j) * 3 + 1];
        const float zj = r[((size_t)b * N_ + j) * 3 + 2];
        const float sc = 2.0f / DMAX;
        #pragma unroll
        for (int m = 0; m < 16; ++m) {
            const float dx = s_ri[m * 3 + 0] - xj;
            const float dy = s_ri[m * 3 + 1] - yj;
            const float dz = s_ri[m * 3 + 2] - zj;
            const float sq = fmaf(dx, dx, fmaf(dy, dy, dz * dz));
            const float d  = sq > 0.0f ? sqrtf(sq) : 0.0f;
            s_x[m * LROW + j] = (h16)(fmaf(d, sc, -1.0f));
        }
    }
    __syncthreads();

    // ================= fragments; wave wv owns j [wv*64, wv*64+64) ==========
    const int wv   = tid >> 6;
    const int lane = tid & 63;
    const int ln   = lane & 15;          // A-row m / B-col n
    const int q    = lane >> 4;          // quad

    h16x8 bfrag[2][4];
    h16x8 x8[2];
    #pragma unroll
    for (int cc = 0; cc < 2; ++cc) {
        const int j0 = wv * 64 + cc * 32;
        x8[cc] = *(const h16x8*)&s_x[ln * LROW + j0 + q * 8];
        #pragma unroll
        for (int ft = 0; ft < 4; ++ft)
            bfrag[cc][ft] = *(const h16x8*)&s_fbT[(ft * 16 + ln) * LROW + j0 + q * 8];
    }
    __syncthreads();   // fbT reads done; arena becomes s_part

    h16x8 ones, twox[2], ta[2], tb[2];
    #pragma unroll
    for (int e = 0; e < 8; ++e) ones[e] = (h16)1.0f;
    #pragma unroll
    for (int cc = 0; cc < 2; ++cc) {
        twox[cc] = x8[cc] + x8[cc];
        ta[cc] = ones;       // T_0
        tb[cc] = x8[cc];     // T_1
    }

    f32x4 facc[4];
    #pragma unroll
    for (int ft = 0; ft < 4; ++ft) facc[ft] = (f32x4){0.f, 0.f, 0.f, 0.f};
    const f32x4 z4 = (f32x4){0.f, 0.f, 0.f, 0.f};

    // ---- K_ Chebyshev terms: 8 MFMAs each, fold c_k, advance recurrence ----
    for (int k = 0; k < K_; ++k) {
        f32x4 a2[4];
        #pragma unroll
        for (int ft = 0; ft < 4; ++ft) {
            a2[ft] = __builtin_amdgcn_mfma_f32_16x16x32_f16(ta[0], bfrag[0][ft], z4, 0, 0, 0);
            a2[ft] = __builtin_amdgcn_mfma_f32_16x16x32_f16(ta[1], bfrag[1][ft], a2[ft], 0, 0, 0);
        }
        #pragma unroll
        for (int ft = 0; ft < 4; ++ft) {
            const float ck = s_c[k * F_ + ft * 16 + ln];
            facc[ft].x = fmaf(ck, a2[ft].x, facc[ft].x);
            facc[ft].y = fmaf(ck, a2[ft].y, facc[ft].y);
            facc[ft].z = fmaf(ck, a2[ft].z, facc[ft].z);
            facc[ft].w = fmaf(ck, a2[ft].w, facc[ft].w);
        }
        #pragma unroll
        for (int cc = 0; cc < 2; ++cc) {
            const h16x8 tn = twox[cc] * tb[cc] - ta[cc];
            ta[cc] = tb[cc];
            tb[cc] = tn;
        }
    }

    // ---- cross-wave reduce: C layout col=ln, row=q*4+rr ----
    #pragma unroll
    for (int ft = 0; ft < 4; ++ft) {
        const float v[4] = {facc[ft].x, facc[ft].y, facc[ft].z, facc[ft].w};
        #pragma unroll
        for (int rr = 0; rr < 4; ++rr)
            s_part[(wv * 16 + q * 4 + rr) * 68 + ft * 16 + ln] = v[rr];
    }
    __syncthreads();

    {
        const int f  = tid & 63;
        const int ig = tid >> 6;
        #pragma unroll
        for (int p = 0; p < 4; ++p) {
            const int i = ig * 4 + p;
            const float s = s_part[(0 * 16 + i) * 68 + f] + s_part[(1 * 16 + i) * 68 + f]
                          + s_part[(2 * 16 + i) * 68 + f] + s_part[(3 * 16 + i) * 68 + f];
            s_fbar[i * F_ + f] = sp(s);
        }
    }
    __syncthreads();

    // ================= pointwise MLP tail: 16 rows in-block =================
    // h2: 16 rows x 128 h = 2048 items
    #pragma unroll
    for (int w = 0; w < 8; ++w) {
        const int item = w * 256 + tid;
        const int row = item >> 7, h = item & 127;
        float z = pc_b1[h];
        #pragma unroll 8
        for (int f = 0; f < F_; ++f)
            z = fmaf(s_fbar[row * F_ + f], pc_w1[f * H_ + h], z);
        s_h2[row * H_ + h] = sp(z);
    }
    __syncthreads();

    // out: 16 rows x 16 p = 256 items
    {
        const int row = tid >> 4, p = tid & 15;
        float z = pc_b2[p];
        #pragma unroll 8
        for (int h = 0; h < H_; ++h)
            z = fmaf(s_h2[row * H_ + h], pc_w2[h * FP_ + p], z);
        out[((size_t)(b * N_ + i0 + row)) * FP_ + p] = sp(z);
    }
}

extern "C" void kernel_launch(void* const* d_in, const int* in_sizes, int n_in,
                              void* d_out, int out_size, void* d_ws, size_t ws_size,
                              hipStream_t stream) {
    const float* r_batch = (const float*)d_in[0];
    const float* f_batch = (const float*)d_in[1];
    const float* mp_w1   = (const float*)d_in[2];
    const float* mp_b1   = (const float*)d_in[3];
    const float* mp_w2   = (const float*)d_in[4];
    const float* mp_b2   = (const float*)d_in[5];
    const float* pc_w1   = (const float*)d_in[6];
    const float* pc_b1   = (const float*)d_in[7];
    const float* pc_w2   = (const float*)d_in[8];
    const float* pc_b2   = (const float*)d_in[9];
    float* out = (float*)d_out;

    pp_fused<<<B_ * (N_ / 16), 256, 0, stream>>>(
        r_batch, f_batch, mp_w1, mp_b1, mp_w2, mp_b2,
        pc_w1, pc_b1, pc_w2, pc_b2, out);
}

// Round 10
// 99.615 us; speedup vs baseline: 1.3882x; 1.3882x over previous
//
#include <hip/hip_runtime.h>
#include <math.h>

#define B_   16
#define N_   256
#define F_   64
#define FP_  16
#define H_   128
#define K_   14                    // Chebyshev terms
#define M_   64                    // Gauss-Chebyshev fit nodes
#define DMAX 1.7320508075688772f   // sqrt(3): r in [0,1]^3
#define PI_F 3.14159265358979323846f
#define LROW 264                   // fbT / x row stride (h16), 256-col rows
#define HP   136                   // 128-col h16 row stride (pad 8)
#define FBP  72                    // 64-col h16 row stride (pad 8)

typedef _Float16 h16;
typedef __attribute__((ext_vector_type(2))) _Float16 h16x2;
typedef __attribute__((ext_vector_type(8))) _Float16 h16x8;
typedef __attribute__((ext_vector_type(4))) float    f32x4;

__device__ __forceinline__ float sp(float x) {
    // numerically stable softplus
    return fmaxf(x, 0.0f) + log1pf(expf(-fabsf(x)));
}

// ONE dispatch. Per block (16-row i-tile): MFMA prelude (Chebyshev fit of the
// per-pair MLP), MFMA main (f_bar = sum_k c_k T_k(X) @ fb), MFMA tail (pointwise
// MLP). grid = B_*(N_/16) = 256 blocks, 256 threads.
__global__ __launch_bounds__(256) void pp_fused(
        const float* __restrict__ r,     const float* __restrict__ fb,
        const float* __restrict__ mp_w1, const float* __restrict__ mp_b1,
        const float* __restrict__ mp_w2, const float* __restrict__ mp_b2,
        const float* __restrict__ pc_w1, const float* __restrict__ pc_b1,
        const float* __restrict__ pc_w2, const float* __restrict__ pc_b2,
        float* __restrict__ out) {
    const int tid  = threadIdx.x;
    const int b    = blockIdx.x >> 4;
    const int i0   = (blockIdx.x & 15) << 4;
    const int wv   = tid >> 6;
    const int lane = tid & 63;
    const int ln   = lane & 15;          // A-row m / B-col n
    const int q    = lane >> 4;          // quad -> k-chunk

    // aliased arena (barrier-sequenced) + static staging buffers
    __shared__ __align__(16) char s_arena[51200];
    __shared__ float s_c[K_ * F_];       // 3584 B
    __shared__ h16   s_w1B[H_ * FBP];    // [h][f]  18432 B
    __shared__ h16   s_w2B[FP_ * HP];    // [p][h]   4352 B
    __shared__ h16   s_fbA[16 * FBP];    // [i][f]   2304 B
    __shared__ h16   s_h2A[16 * HP];     // [i][h]   4352 B
    __shared__ float s_ri[48];

    h16*   s_hidA = (h16*)s_arena;                 // [64][HP]  prelude A
    h16*   s_w2T  = (h16*)(s_arena + 17408);       // [f][h]    prelude B
    float* s_vals = (float*)(s_arena + 34816);     // [64][64]
    h16*   s_fbT  = (h16*)s_arena;                 // [64][LROW] main B
    h16*   s_x    = (h16*)(s_arena + 33792);       // [16][LROW] main A
    float* s_part = (float*)s_arena;               // [64][68]  C partials

    // ===== stage-once: i-coords, tail weights (f16, B-layout rows) =========
    if (tid < 48) s_ri[tid] = r[((size_t)b * N_ + i0) * 3 + tid];
    #pragma unroll
    for (int e = 0; e < 8; ++e) {        // w1B[h][f] = pc_w1[f*H+h]
        const int idx = e * 256 + tid;   // float4 over h
        const int f = idx >> 5, h4 = idx & 31;
        const float4 v = *(const float4*)(pc_w1 + f * H_ + h4 * 4);
        s_w1B[(h4 * 4 + 0) * FBP + f] = (h16)v.x;
        s_w1B[(h4 * 4 + 1) * FBP + f] = (h16)v.y;
        s_w1B[(h4 * 4 + 2) * FBP + f] = (h16)v.z;
        s_w1B[(h4 * 4 + 3) * FBP + f] = (h16)v.w;
    }
    #pragma unroll
    for (int e = 0; e < 8; ++e) {        // w2B[p][h] = pc_w2[h*FP+p]
        const int idx = e * 256 + tid;
        const int h = idx >> 4, p = idx & 15;
        s_w2B[p * HP + h] = (h16)pc_w2[idx];
    }

    // ===== P1: hidden layer at 64 nodes (f16, A-layout) + stage mp_w2^T ====
    {
        const int m  = tid >> 2;
        const int h0 = (tid & 3) * 32;
        const float th = PI_F * ((float)m + 0.5f) / (float)M_;
        const float d  = (__cosf(th) + 1.0f) * 0.5f * DMAX;
        #pragma unroll 8
        for (int hh = 0; hh < 32; ++hh) {
            const int h = h0 + hh;
            s_hidA[m * HP + h] = (h16)sp(fmaf(d, mp_w1[h], mp_b1[h]));
        }
    }
    #pragma unroll
    for (int e = 0; e < 8; ++e) {        // w2T[f][h] = mp_w2[h*F+f]
        const int idx = e * 256 + tid;   // float4 over f
        const int h = idx >> 4, f4 = idx & 15;
        const float4 v = *(const float4*)(mp_w2 + h * F_ + f4 * 4);
        s_w2T[(f4 * 4 + 0) * HP + h] = (h16)v.x;
        s_w2T[(f4 * 4 + 1) * HP + h] = (h16)v.y;
        s_w2T[(f4 * 4 + 2) * HP + h] = (h16)v.z;
        s_w2T[(f4 * 4 + 3) * HP + h] = (h16)v.w;
    }
    __syncthreads();

    // ===== P2: vals(64x64) = sp(hid @ w2 + b2) via MFMA ====================
    {
        f32x4 vacc[4];
        #pragma unroll
        for (int ft = 0; ft < 4; ++ft) vacc[ft] = (f32x4){0.f, 0.f, 0.f, 0.f};
        #pragma unroll
        for (int ks = 0; ks < 4; ++ks) {
            const h16x8 af = *(const h16x8*)&s_hidA[(wv * 16 + ln) * HP + ks * 32 + q * 8];
            #pragma unroll
            for (int ft = 0; ft < 4; ++ft) {
                const h16x8 bf = *(const h16x8*)&s_w2T[(ft * 16 + ln) * HP + ks * 32 + q * 8];
                vacc[ft] = __builtin_amdgcn_mfma_f32_16x16x32_f16(af, bf, vacc[ft], 0, 0, 0);
            }
        }
        #pragma unroll
        for (int ft = 0; ft < 4; ++ft) {
            const float b2v = mp_b2[ft * 16 + ln];
            const float vv[4] = {vacc[ft].x, vacc[ft].y, vacc[ft].z, vacc[ft].w};
            #pragma unroll
            for (int rr = 0; rr < 4; ++rr)
                s_vals[(wv * 16 + q * 4 + rr) * F_ + ft * 16 + ln] = sp(vv[rr] + b2v);
        }
    }
    __syncthreads();

    // ===== P3: DCT c[k][f] = w_k/M sum_m vals[m][f] cos(k theta_m) =========
    {
        const int f = tid & 63, kq = tid >> 6;     // kk = kq, kq+4, kq+8, (kq+12)
        float s0 = 0.f, s1 = 0.f, s2 = 0.f, s3 = 0.f;
        for (int m = 0; m < M_; ++m) {
            const float v  = s_vals[m * F_ + f];
            const float th = PI_F * ((float)m + 0.5f) / (float)M_;
            s0 = fmaf(v, __cosf((float)kq * th), s0);
            s1 = fmaf(v, __cosf((float)(kq + 4) * th), s1);
            s2 = fmaf(v, __cosf((float)(kq + 8) * th), s2);
            s3 = fmaf(v, __cosf((float)(kq + 12) * th), s3);
        }
        const float inv = 1.0f / (float)M_;
        s_c[kq * F_ + f]        = ((kq == 0) ? 1.0f : 2.0f) * s0 * inv;
        s_c[(kq + 4) * F_ + f]  = 2.0f * s1 * inv;
        s_c[(kq + 8) * F_ + f]  = 2.0f * s2 * inv;
        if (kq + 12 < K_) s_c[(kq + 12) * F_ + f] = 2.0f * s3 * inv;
    }
    __syncthreads();   // vals dead; arena free for fbT/x

    // ===== main stage: fb^T (f32->f16) + x tile (verbatim from R9) =========
    {
        const float* fbb = fb + (size_t)b * N_ * F_;
        const int f4 = tid & 15;
        const int jp = tid >> 4;
        #pragma unroll
        for (int jb = 0; jb < 8; ++jb) {
            const int j0 = jb * 32 + jp * 2;
            const float4 v0 = *(const float4*)(fbb + (size_t)j0 * F_ + f4 * 4);
            const float4 v1 = *(const float4*)(fbb + (size_t)(j0 + 1) * F_ + f4 * 4);
            const float a0[4] = {v0.x, v0.y, v0.z, v0.w};
            const float a1[4] = {v1.x, v1.y, v1.z, v1.w};
            #pragma unroll
            for (int ff = 0; ff < 4; ++ff) {
                h16x2 pk; pk.x = (h16)a0[ff]; pk.y = (h16)a1[ff];
                *(h16x2*)&s_fbT[(f4 * 4 + ff) * LROW + j0] = pk;
            }
        }
    }
    {
        const int j = tid;
        const float xj = r[((size_t)b * N_ + j) * 3 + 0];
        const float yj = r[((size_t)b * N_ + j) * 3 + 1];
        const float zj = r[((size_t)b * N_ + j) * 3 + 2];
        const float sc = 2.0f / DMAX;
        #pragma unroll
        for (int m = 0; m < 16; ++m) {
            const float dx = s_ri[m * 3 + 0] - xj;
            const float dy = s_ri[m * 3 + 1] - yj;
            const float dz = s_ri[m * 3 + 2] - zj;
            const float sq = fmaf(dx, dx, fmaf(dy, dy, dz * dz));
            const float d  = sq > 0.0f ? sqrtf(sq) : 0.0f;
            s_x[m * LROW + j] = (h16)(fmaf(d, sc, -1.0f));
        }
    }
    __syncthreads();

    // ===== fragments; wave wv owns j [wv*64, wv*64+64) =====================
    h16x8 bfrag[2][4];
    h16x8 x8[2];
    #pragma unroll
    for (int cc = 0; cc < 2; ++cc) {
        const int j0 = wv * 64 + cc * 32;
        x8[cc] = *(const h16x8*)&s_x[ln * LROW + j0 + q * 8];
        #pragma unroll
        for (int ft = 0; ft < 4; ++ft)
            bfrag[cc][ft] = *(const h16x8*)&s_fbT[(ft * 16 + ln) * LROW + j0 + q * 8];
    }
    __syncthreads();   // fbT/x reads done; arena becomes s_part

    h16x8 ones, twox[2], ta[2], tb[2];
    #pragma unroll
    for (int e = 0; e < 8; ++e) ones[e] = (h16)1.0f;
    #pragma unroll
    for (int cc = 0; cc < 2; ++cc) {
        twox[cc] = x8[cc] + x8[cc];
        ta[cc] = ones;       // T_0
        tb[cc] = x8[cc];     // T_1
    }

    f32x4 facc[4];
    #pragma unroll
    for (int ft = 0; ft < 4; ++ft) facc[ft] = (f32x4){0.f, 0.f, 0.f, 0.f};
    const f32x4 z4 = (f32x4){0.f, 0.f, 0.f, 0.f};

    for (int k = 0; k < K_; ++k) {
        f32x4 a2[4];
        #pragma unroll
        for (int ft = 0; ft < 4; ++ft) {
            a2[ft] = __builtin_amdgcn_mfma_f32_16x16x32_f16(ta[0], bfrag[0][ft], z4, 0, 0, 0);
            a2[ft] = __builtin_amdgcn_mfma_f32_16x16x32_f16(ta[1], bfrag[1][ft], a2[ft], 0, 0, 0);
        }
        #pragma unroll
        for (int ft = 0; ft < 4; ++ft) {
            const float ck = s_c[k * F_ + ft * 16 + ln];
            facc[ft].x = fmaf(ck, a2[ft].x, facc[ft].x);
            facc[ft].y = fmaf(ck, a2[ft].y, facc[ft].y);
            facc[ft].z = fmaf(ck, a2[ft].z, facc[ft].z);
            facc[ft].w = fmaf(ck, a2[ft].w, facc[ft].w);
        }
        #pragma unroll
        for (int cc = 0; cc < 2; ++cc) {
            const h16x8 tn = twox[cc] * tb[cc] - ta[cc];
            ta[cc] = tb[cc];
            tb[cc] = tn;
        }
    }

    // ---- cross-wave C partials (layout col=ln, row=q*4+rr) ----
    #pragma unroll
    for (int ft = 0; ft < 4; ++ft) {
        const float v[4] = {facc[ft].x, facc[ft].y, facc[ft].z, facc[ft].w};
        #pragma unroll
        for (int rr = 0; rr < 4; ++rr)
            s_part[(wv * 16 + q * 4 + rr) * 68 + ft * 16 + ln] = v[rr];
    }
    __syncthreads();

    // ---- reduce 4 waves -> f_bar (f16, A-layout rows i) ----
    {
        const int f  = tid & 63;
        const int ig = tid >> 6;
        #pragma unroll
        for (int p = 0; p < 4; ++p) {
            const int i = ig * 4 + p;
            const float s = s_part[(0 * 16 + i) * 68 + f] + s_part[(1 * 16 + i) * 68 + f]
                          + s_part[(2 * 16 + i) * 68 + f] + s_part[(3 * 16 + i) * 68 + f];
            s_fbA[i * FBP + f] = (h16)sp(s);
        }
    }
    __syncthreads();

    // ===== tail 1: h2(16x128) = sp(fbar @ pc_w1 + b1), wave wv: n-tiles 2wv,2wv+1
    {
        #pragma unroll
        for (int t2 = 0; t2 < 2; ++t2) {
            const int nt = wv * 2 + t2;
            f32x4 hacc = (f32x4){0.f, 0.f, 0.f, 0.f};
            #pragma unroll
            for (int ks = 0; ks < 2; ++ks) {
                const h16x8 af = *(const h16x8*)&s_fbA[ln * FBP + ks * 32 + q * 8];
                const h16x8 bf = *(const h16x8*)&s_w1B[(nt * 16 + ln) * FBP + ks * 32 + q * 8];
                hacc = __builtin_amdgcn_mfma_f32_16x16x32_f16(af, bf, hacc, 0, 0, 0);
            }
            const float b1v = pc_b1[nt * 16 + ln];
            const float hv[4] = {hacc.x, hacc.y, hacc.z, hacc.w};
            #pragma unroll
            for (int rr = 0; rr < 4; ++rr)
                s_h2A[(q * 4 + rr) * HP + nt * 16 + ln] = (h16)sp(hv[rr] + b1v);
        }
    }
    __syncthreads();

    // ===== tail 2: out(16x16) = sp(h2 @ pc_w2 + b2); waves duplicate, wv0 writes
    {
        f32x4 oacc = (f32x4){0.f, 0.f, 0.f, 0.f};
        #pragma unroll
        for (int ks = 0; ks < 4; ++ks) {
            const h16x8 af = *(const h16x8*)&s_h2A[ln * HP + ks * 32 + q * 8];
            const h16x8 bf = *(const h16x8*)&s_w2B[ln * HP + ks * 32 + q * 8];
            oacc = __builtin_amdgcn_mfma_f32_16x16x32_f16(af, bf, oacc, 0, 0, 0);
        }
        if (wv == 0) {
            const float b2v = pc_b2[ln];
            const float ov[4] = {oacc.x, oacc.y, oacc.z, oacc.w};
            #pragma unroll
            for (int rr = 0; rr < 4; ++rr)
                out[((size_t)(b * N_ + i0 + q * 4 + rr)) * FP_ + ln] = sp(ov[rr] + b2v);
        }
    }
}

extern "C" void kernel_launch(void* const* d_in, const int* in_sizes, int n_in,
                              void* d_out, int out_size, void* d_ws, size_t ws_size,
                              hipStream_t stream) {
    const float* r_batch = (const float*)d_in[0];
    const float* f_batch = (const float*)d_in[1];
    const float* mp_w1   = (const float*)d_in[2];
    const float* mp_b1   = (const float*)d_in[3];
    const float* mp_w2   = (const float*)d_in[4];
    const float* mp_b2   = (const float*)d_in[5];
    const float* pc_w1   = (const float*)d_in[6];
    const float* pc_b1   = (const float*)d_in[7];
    const float* pc_w2   = (const float*)d_in[8];
    const float* pc_b2   = (const float*)d_in[9];
    float* out = (float*)d_out;

    pp_fused<<<B_ * (N_ / 16), 256, 0, stream>>>(
        r_batch, f_batch, mp_w1, mp_b1, mp_w2, mp_b2,
        pc_w1, pc_b1, pc_w2, pc_b2, out);
}

// Round 12
// 87.729 us; speedup vs baseline: 1.5763x; 1.1355x over previous
//
#include <hip/hip_runtime.h>
#include <math.h>

#define B_   16
#define N_   256
#define F_   64
#define FP_  16
#define H_   128
#define K_   14                    // Chebyshev terms
#define M_   64                    // Gauss-Chebyshev fit nodes
#define DMAX 1.7320508075688772f   // sqrt(3): r in [0,1]^3
#define PI_F 3.14159265358979323846f
#define LROW 264                   // fbT / x row stride (h16), 256-col rows
#define HP   136                   // 128-col h16 row stride (pad 8)
#define FBP  72                    // 64-col h16 row stride (pad 8)

typedef _Float16 h16;
typedef __attribute__((ext_vector_type(2))) _Float16 h16x2;
typedef __attribute__((ext_vector_type(8))) _Float16 h16x8;
typedef __attribute__((ext_vector_type(4))) float    f32x4;

__device__ __forceinline__ float sp(float x) {
    // softplus via native v_exp/v_log: 1+e^{-|x|} in (1,2], no cancellation
    return fmaxf(x, 0.0f) + __logf(1.0f + __expf(-fabsf(x)));
}

// ONE dispatch. Per block (16-row i-tile): MFMA prelude (Chebyshev fit of the
// per-pair MLP), MFMA main (f_bar = sum_k c_k T_k(X) @ fb), MFMA tail (pointwise
// MLP). grid = B_*(N_/16) = 256 blocks, 256 threads.
__global__ __launch_bounds__(256) void pp_fused(
        const float* __restrict__ r,     const float* __restrict__ fb,
        const float* __restrict__ mp_w1, const float* __restrict__ mp_b1,
        const float* __restrict__ mp_w2, const float* __restrict__ mp_b2,
        const float* __restrict__ pc_w1, const float* __restrict__ pc_b1,
        const float* __restrict__ pc_w2, const float* __restrict__ pc_b2,
        float* __restrict__ out) {
    const int tid  = threadIdx.x;
    const int b    = blockIdx.x >> 4;
    const int i0   = (blockIdx.x & 15) << 4;
    const int wv   = tid >> 6;
    const int lane = tid & 63;
    const int ln   = lane & 15;          // A-row m / B-col n
    const int q    = lane >> 4;          // quad -> k-chunk

    // aliased arena (barrier-sequenced) + static staging buffers
    __shared__ __align__(16) char s_arena[51200];
    __shared__ float s_c[K_ * F_];       // 3584 B
    __shared__ h16   s_w1B[H_ * FBP];    // [h][f]  18432 B
    __shared__ h16   s_w2B[FP_ * HP];    // [p][h]   4352 B
    __shared__ h16   s_fbA[16 * FBP];    // [i][f]   2304 B
    __shared__ h16   s_h2A[16 * HP];     // [i][h]   4352 B
    __shared__ float s_ri[48];

    h16*   s_hidA = (h16*)s_arena;                 // [64][HP]  prelude A
    h16*   s_w2T  = (h16*)(s_arena + 17408);       // [f][h]    prelude B
    float* s_vals = (float*)(s_arena + 34816);     // [64][64]
    h16*   s_fbT  = (h16*)s_arena;                 // [64][LROW] main B
    h16*   s_x    = (h16*)(s_arena + 33792);       // [16][LROW] main A
    float* s_part = (float*)s_arena;               // [64][68]  C partials

    // ===== stage-once: i-coords, tail weights (f16, B-layout rows) =========
    if (tid < 48) s_ri[tid] = r[((size_t)b * N_ + i0) * 3 + tid];
    #pragma unroll
    for (int e = 0; e < 8; ++e) {        // w1B[h][f] = pc_w1[f*H+h]
        const int idx = e * 256 + tid;   // float4 over h
        const int f = idx >> 5, h4 = idx & 31;
        const float4 v = *(const float4*)(pc_w1 + f * H_ + h4 * 4);
        s_w1B[(h4 * 4 + 0) * FBP + f] = (h16)v.x;
        s_w1B[(h4 * 4 + 1) * FBP + f] = (h16)v.y;
        s_w1B[(h4 * 4 + 2) * FBP + f] = (h16)v.z;
        s_w1B[(h4 * 4 + 3) * FBP + f] = (h16)v.w;
    }
    #pragma unroll
    for (int e = 0; e < 8; ++e) {        // w2B[p][h] = pc_w2[h*FP+p]
        const int idx = e * 256 + tid;
        const int h = idx >> 4, p = idx & 15;
        s_w2B[p * HP + h] = (h16)pc_w2[idx];
    }

    // ===== P1: hidden layer at 64 nodes (f16, A-layout) + stage mp_w2^T ====
    {
        const int m  = tid >> 2;
        const int h0 = (tid & 3) * 32;
        const float th = PI_F * ((float)m + 0.5f) / (float)M_;
        const float d  = (__cosf(th) + 1.0f) * 0.5f * DMAX;
        #pragma unroll 8
        for (int hh = 0; hh < 32; ++hh) {
            const int h = h0 + hh;
            s_hidA[m * HP + h] = (h16)sp(fmaf(d, mp_w1[h], mp_b1[h]));
        }
    }
    #pragma unroll
    for (int e = 0; e < 8; ++e) {        // w2T[f][h] = mp_w2[h*F+f]
        const int idx = e * 256 + tid;   // float4 over f
        const int h = idx >> 4, f4 = idx & 15;
        const float4 v = *(const float4*)(mp_w2 + h * F_ + f4 * 4);
        s_w2T[(f4 * 4 + 0) * HP + h] = (h16)v.x;
        s_w2T[(f4 * 4 + 1) * HP + h] = (h16)v.y;
        s_w2T[(f4 * 4 + 2) * HP + h] = (h16)v.z;
        s_w2T[(f4 * 4 + 3) * HP + h] = (h16)v.w;
    }
    __syncthreads();

    // ===== P2: vals(64x64) = sp(hid @ w2 + b2) via MFMA ====================
    {
        f32x4 vacc[4];
        #pragma unroll
        for (int ft = 0; ft < 4; ++ft) vacc[ft] = (f32x4){0.f, 0.f, 0.f, 0.f};
        #pragma unroll
        for (int ks = 0; ks < 4; ++ks) {
            const h16x8 af = *(const h16x8*)&s_hidA[(wv * 16 + ln) * HP + ks * 32 + q * 8];
            #pragma unroll
            for (int ft = 0; ft < 4; ++ft) {
                const h16x8 bf = *(const h16x8*)&s_w2T[(ft * 16 + ln) * HP + ks * 32 + q * 8];
                vacc[ft] = __builtin_amdgcn_mfma_f32_16x16x32_f16(af, bf, vacc[ft], 0, 0, 0);
            }
        }
        #pragma unroll
        for (int ft = 0; ft < 4; ++ft) {
            const float b2v = mp_b2[ft * 16 + ln];
            const float vv[4] = {vacc[ft].x, vacc[ft].y, vacc[ft].z, vacc[ft].w};
            #pragma unroll
            for (int rr = 0; rr < 4; ++rr)
                s_vals[(wv * 16 + q * 4 + rr) * F_ + ft * 16 + ln] = sp(vv[rr] + b2v);
        }
    }
    __syncthreads();

    // ===== P3: DCT c[k][f] = w_k/M sum_m vals[m][f] cos(k theta_m) =========
    {
        const int f = tid & 63, kq = tid >> 6;     // kk = kq, kq+4, kq+8, (kq+12)
        float s0 = 0.f, s1 = 0.f, s2 = 0.f, s3 = 0.f;
        for (int m = 0; m < M_; ++m) {
            const float v  = s_vals[m * F_ + f];
            const float th = PI_F * ((float)m + 0.5f) / (float)M_;
            s0 = fmaf(v, __cosf((float)kq * th), s0);
            s1 = fmaf(v, __cosf((float)(kq + 4) * th), s1);
            s2 = fmaf(v, __cosf((float)(kq + 8) * th), s2);
            s3 = fmaf(v, __cosf((float)(kq + 12) * th), s3);
        }
        const float inv = 1.0f / (float)M_;
        s_c[kq * F_ + f]        = ((kq == 0) ? 1.0f : 2.0f) * s0 * inv;
        s_c[(kq + 4) * F_ + f]  = 2.0f * s1 * inv;
        s_c[(kq + 8) * F_ + f]  = 2.0f * s2 * inv;
        if (kq + 12 < K_) s_c[(kq + 12) * F_ + f] = 2.0f * s3 * inv;
    }
    __syncthreads();   // vals dead; arena free for fbT/x

    // ===== main stage: fb^T (f32->f16) + x tile ============================
    {
        const float* fbb = fb + (size_t)b * N_ * F_;
        const int f4 = tid & 15;
        const int jp = tid >> 4;
        #pragma unroll
        for (int jb = 0; jb < 8; ++jb) {
            const int j0 = jb * 32 + jp * 2;
            const float4 v0 = *(const float4*)(fbb + (size_t)j0 * F_ + f4 * 4);
            const float4 v1 = *(const float4*)(fbb + (size_t)(j0 + 1) * F_ + f4 * 4);
            const float a0[4] = {v0.x, v0.y, v0.z, v0.w};
            const float a1[4] = {v1.x, v1.y, v1.z, v1.w};
            #pragma unroll
            for (int ff = 0; ff < 4; ++ff) {
                h16x2 pk; pk.x = (h16)a0[ff]; pk.y = (h16)a1[ff];
                *(h16x2*)&s_fbT[(f4 * 4 + ff) * LROW + j0] = pk;
            }
        }
    }
    {
        const int j = tid;
        const float xj = r[((size_t)b * N_ + j) * 3 + 0];
        const float yj = r[((size_t)b * N_ + j) * 3 + 1];
        const float zj = r[((size_t)b * N_ + j) * 3 + 2];
        const float sc = 2.0f / DMAX;
        #pragma unroll
        for (int m = 0; m < 16; ++m) {
            const float dx = s_ri[m * 3 + 0] - xj;
            const float dy = s_ri[m * 3 + 1] - yj;
            const float dz = s_ri[m * 3 + 2] - zj;
            const float sq = fmaf(dx, dx, fmaf(dy, dy, dz * dz));
            const float d  = sq > 0.0f ? sqrtf(sq) : 0.0f;
            s_x[m * LROW + j] = (h16)(fmaf(d, sc, -1.0f));
        }
    }
    __syncthreads();

    // ===== fragments; wave wv owns j [wv*64, wv*64+64) =====================
    h16x8 bfrag[2][4];
    h16x8 x8[2];
    #pragma unroll
    for (int cc = 0; cc < 2; ++cc) {
        const int j0 = wv * 64 + cc * 32;
        x8[cc] = *(const h16x8*)&s_x[ln * LROW + j0 + q * 8];
        #pragma unroll
        for (int ft = 0; ft < 4; ++ft)
            bfrag[cc][ft] = *(const h16x8*)&s_fbT[(ft * 16 + ln) * LROW + j0 + q * 8];
    }
    __syncthreads();   // fbT/x reads done; arena becomes s_part

    h16x8 ones, twox[2], ta[2], tb[2];
    #pragma unroll
    for (int e = 0; e < 8; ++e) ones[e] = (h16)1.0f;
    #pragma unroll
    for (int cc = 0; cc < 2; ++cc) {
        twox[cc] = x8[cc] + x8[cc];
        ta[cc] = ones;       // T_0
        tb[cc] = x8[cc];     // T_1
    }

    f32x4 facc[4];
    #pragma unroll
    for (int ft = 0; ft < 4; ++ft) facc[ft] = (f32x4){0.f, 0.f, 0.f, 0.f};
    const f32x4 z4 = (f32x4){0.f, 0.f, 0.f, 0.f};

    for (int k = 0; k < K_; ++k) {
        f32x4 a2[4];
        #pragma unroll
        for (int ft = 0; ft < 4; ++ft) {
            a2[ft] = __builtin_amdgcn_mfma_f32_16x16x32_f16(ta[0], bfrag[0][ft], z4, 0, 0, 0);
            a2[ft] = __builtin_amdgcn_mfma_f32_16x16x32_f16(ta[1], bfrag[1][ft], a2[ft], 0, 0, 0);
        }
        #pragma unroll
        for (int ft = 0; ft < 4; ++ft) {
            const float ck = s_c[k * F_ + ft * 16 + ln];
            facc[ft].x = fmaf(ck, a2[ft].x, facc[ft].x);
            facc[ft].y = fmaf(ck, a2[ft].y, facc[ft].y);
            facc[ft].z = fmaf(ck, a2[ft].z, facc[ft].z);
            facc[ft].w = fmaf(ck, a2[ft].w, facc[ft].w);
        }
        #pragma unroll
        for (int cc = 0; cc < 2; ++cc) {
            const h16x8 tn = twox[cc] * tb[cc] - ta[cc];
            ta[cc] = tb[cc];
            tb[cc] = tn;
        }
    }

    // ---- cross-wave C partials (layout col=ln, row=q*4+rr) ----
    #pragma unroll
    for (int ft = 0; ft < 4; ++ft) {
        const float v[4] = {facc[ft].x, facc[ft].y, facc[ft].z, facc[ft].w};
        #pragma unroll
        for (int rr = 0; rr < 4; ++rr)
            s_part[(wv * 16 + q * 4 + rr) * 68 + ft * 16 + ln] = v[rr];
    }
    __syncthreads();

    // ---- reduce 4 waves -> f_bar (f16, A-layout rows i) ----
    {
        const int f  = tid & 63;
        const int ig = tid >> 6;
        #pragma unroll
        for (int p = 0; p < 4; ++p) {
            const int i = ig * 4 + p;
            const float s = s_part[(0 * 16 + i) * 68 + f] + s_part[(1 * 16 + i) * 68 + f]
                          + s_part[(2 * 16 + i) * 68 + f] + s_part[(3 * 16 + i) * 68 + f];
            s_fbA[i * FBP + f] = (h16)sp(s);
        }
    }
    __syncthreads();

    // ===== tail 1: h2(16x128) = sp(fbar @ pc_w1 + b1), wave wv: n-tiles 2wv,2wv+1
    {
        #pragma unroll
        for (int t2 = 0; t2 < 2; ++t2) {
            const int nt = wv * 2 + t2;
            f32x4 hacc = (f32x4){0.f, 0.f, 0.f, 0.f};
            #pragma unroll
            for (int ks = 0; ks < 2; ++ks) {
                const h16x8 af = *(const h16x8*)&s_fbA[ln * FBP + ks * 32 + q * 8];
                const h16x8 bf = *(const h16x8*)&s_w1B[(nt * 16 + ln) * FBP + ks * 32 + q * 8];
                hacc = __builtin_amdgcn_mfma_f32_16x16x32_f16(af, bf, hacc, 0, 0, 0);
            }
            const float b1v = pc_b1[nt * 16 + ln];
            const float hv[4] = {hacc.x, hacc.y, hacc.z, hacc.w};
            #pragma unroll
            for (int rr = 0; rr < 4; ++rr)
                s_h2A[(q * 4 + rr) * HP + nt * 16 + ln] = (h16)sp(hv[rr] + b1v);
        }
    }
    __syncthreads();

    // ===== tail 2: out(16x16) = sp(h2 @ pc_w2 + b2); waves duplicate, wv0 writes
    {
        f32x4 oacc = (f32x4){0.f, 0.f, 0.f, 0.f};
        #pragma unroll
        for (int ks = 0; ks < 4; ++ks) {
            const h16x8 af = *(const h16x8*)&s_h2A[ln * HP + ks * 32 + q * 8];
            const h16x8 bf = *(const h16x8*)&s_w2B[ln * HP + ks * 32 + q * 8];
            oacc = __builtin_amdgcn_mfma_f32_16x16x32_f16(af, bf, oacc, 0, 0, 0);
        }
        if (wv == 0) {
            const float b2v = pc_b2[ln];
            const float ov[4] = {oacc.x, oacc.y, oacc.z, oacc.w};
            #pragma unroll
            for (int rr = 0; rr < 4; ++rr)
                out[((size_t)(b * N_ + i0 + q * 4 + rr)) * FP_ + ln] = sp(ov[rr] + b2v);
        }
    }
}

extern "C" void kernel_launch(void* const* d_in, const int* in_sizes, int n_in,
                              void* d_out, int out_size, void* d_ws, size_t ws_size,
                              hipStream_t stream) {
    const float* r_batch = (const float*)d_in[0];
    const float* f_batch = (const float*)d_in[1];
    const float* mp_w1   = (const float*)d_in[2];
    const float* mp_b1   = (const float*)d_in[3];
    const float* mp_w2   = (const float*)d_in[4];
    const float* mp_b2   = (const float*)d_in[5];
    const float* pc_w1   = (const float*)d_in[6];
    const float* pc_b1   = (const float*)d_in[7];
    const float* pc_w2   = (const float*)d_in[8];
    const float* pc_b2   = (const float*)d_in[9];
    float* out = (float*)d_out;

    pp_fused<<<B_ * (N_ / 16), 256, 0, stream>>>(
        r_batch, f_batch, mp_w1, mp_b1, mp_w2, mp_b2,
        pc_w1, pc_b1, pc_w2, pc_b2, out);
}

// Round 13
// 85.458 us; speedup vs baseline: 1.6182x; 1.0266x over previous
//
#include <hip/hip_runtime.h>
#include <math.h>

#define B_   16
#define N_   256
#define F_   64
#define FP_  16
#define H_   128
#define K_   14                    // Chebyshev terms
#define M_   64                    // Gauss-Chebyshev fit nodes
#define DMAX 1.7320508075688772f   // sqrt(3): r in [0,1]^3
#define PI_F 3.14159265358979323846f
#define LROW 264                   // fbT / x row stride (h16), 256-col rows
#define HP   136                   // 128-col h16 row stride (pad 8)
#define FBP  72                    // 64-col h16 row stride (pad 8)
#define MP   72                    // valsT row stride (h16), 64 m-cols (pad 8)

typedef _Float16 h16;
typedef __attribute__((ext_vector_type(2))) _Float16 h16x2;
typedef __attribute__((ext_vector_type(4))) _Float16 h16x4;
typedef __attribute__((ext_vector_type(8))) _Float16 h16x8;
typedef __attribute__((ext_vector_type(4))) float    f32x4;

__device__ __forceinline__ float sp(float x) {
    // softplus via native v_exp/v_log: 1+e^{-|x|} in (1,2], no cancellation
    return fmaxf(x, 0.0f) + __logf(1.0f + __expf(-fabsf(x)));
}

// ONE dispatch. Per block (16-row i-tile): MFMA prelude (Chebyshev fit of the
// per-pair MLP, DCT also via MFMA), MFMA main (f_bar = sum_k c_k T_k(X) @ fb),
// MFMA tail (pointwise MLP). grid = B_*(N_/16) = 256 blocks, 256 threads.
__global__ __launch_bounds__(256) void pp_fused(
        const float* __restrict__ r,     const float* __restrict__ fb,
        const float* __restrict__ mp_w1, const float* __restrict__ mp_b1,
        const float* __restrict__ mp_w2, const float* __restrict__ mp_b2,
        const float* __restrict__ pc_w1, const float* __restrict__ pc_b1,
        const float* __restrict__ pc_w2, const float* __restrict__ pc_b2,
        float* __restrict__ out) {
    const int tid  = threadIdx.x;
    const int b    = blockIdx.x >> 4;
    const int i0   = (blockIdx.x & 15) << 4;
    const int wv   = tid >> 6;
    const int lane = tid & 63;
    const int ln   = lane & 15;          // A-row m / B-col n
    const int q    = lane >> 4;          // quad -> k-chunk

    // aliased arena (barrier-sequenced) + static staging buffers
    __shared__ __align__(16) char s_arena[51200];
    __shared__ float s_c[K_ * F_];       // 3584 B
    __shared__ h16   s_w1B[H_ * FBP];    // [h][f]  18432 B
    __shared__ h16   s_w2B[FP_ * HP];    // [p][h]   4352 B
    __shared__ h16   s_fbA[16 * FBP];    // [i][f]   2304 B
    __shared__ h16   s_h2A[16 * HP];     // [i][h]   4352 B
    __shared__ float s_ri[48];

    h16*   s_hidA  = (h16*)s_arena;                 // [64][HP]   prelude A  [0,17408)
    h16*   s_w2T   = (h16*)(s_arena + 17408);       // [f][h]     prelude B  [17408,34816)
    h16*   s_valsT = (h16*)(s_arena + 34816);       // [64][MP]   f16        [34816,44032)
    h16*   s_fbT   = (h16*)s_arena;                 // [64][LROW] main B     [0,33792)
    h16*   s_x     = (h16*)(s_arena + 33792);       // [16][LROW] main A     [33792,42240)? no:
    // NOTE: s_x must not overlap s_valsT (read concurrently) -> keep s_x static below
    float* s_part  = (float*)s_arena;               // [64][68]   C partials

    __shared__ h16 s_xs[16 * LROW];      // x tile, static (8448 B) — avoids valsT overlap

    // ===== prefetch: fb tile (16 float4) + own r coords into registers =====
    const float* fbb = fb + (size_t)b * N_ * F_;
    const int f4 = tid & 15;
    const int jp = tid >> 4;
    float4 pf0[8], pf1[8];
    #pragma unroll
    for (int jb = 0; jb < 8; ++jb) {
        const int j0 = jb * 32 + jp * 2;
        pf0[jb] = *(const float4*)(fbb + (size_t)j0 * F_ + f4 * 4);
        pf1[jb] = *(const float4*)(fbb + (size_t)(j0 + 1) * F_ + f4 * 4);
    }
    const float xj = r[((size_t)b * N_ + tid) * 3 + 0];
    const float yj = r[((size_t)b * N_ + tid) * 3 + 1];
    const float zj = r[((size_t)b * N_ + tid) * 3 + 2];

    // ===== stage-once: i-coords, tail weights (f16, B-layout rows) =========
    if (tid < 48) s_ri[tid] = r[((size_t)b * N_ + i0) * 3 + tid];
    #pragma unroll
    for (int e = 0; e < 8; ++e) {        // w1B[h][f] = pc_w1[f*H+h]
        const int idx = e * 256 + tid;   // float4 over h
        const int f = idx >> 5, h4 = idx & 31;
        const float4 v = *(const float4*)(pc_w1 + f * H_ + h4 * 4);
        s_w1B[(h4 * 4 + 0) * FBP + f] = (h16)v.x;
        s_w1B[(h4 * 4 + 1) * FBP + f] = (h16)v.y;
        s_w1B[(h4 * 4 + 2) * FBP + f] = (h16)v.z;
        s_w1B[(h4 * 4 + 3) * FBP + f] = (h16)v.w;
    }
    #pragma unroll
    for (int e = 0; e < 8; ++e) {        // w2B[p][h] = pc_w2[h*FP+p]
        const int idx = e * 256 + tid;
        const int h = idx >> 4, p = idx & 15;
        s_w2B[p * HP + h] = (h16)pc_w2[idx];
    }

    // ===== P1: hidden layer at 64 nodes (f16, A-layout), vectorized ========
    {
        const int m  = tid >> 2;
        const int h0 = (tid & 3) * 32;
        const float th = PI_F * ((float)m + 0.5f) / (float)M_;
        const float d  = (__cosf(th) + 1.0f) * 0.5f * DMAX;
        #pragma unroll
        for (int hq = 0; hq < 8; ++hq) {
            const float4 w = *(const float4*)(mp_w1 + h0 + hq * 4);
            const float4 bb = *(const float4*)(mp_b1 + h0 + hq * 4);
            h16x4 hv;
            hv.x = (h16)sp(fmaf(d, w.x, bb.x));
            hv.y = (h16)sp(fmaf(d, w.y, bb.y));
            hv.z = (h16)sp(fmaf(d, w.z, bb.z));
            hv.w = (h16)sp(fmaf(d, w.w, bb.w));
            *(h16x4*)&s_hidA[m * HP + h0 + hq * 4] = hv;
        }
    }
    #pragma unroll
    for (int e = 0; e < 8; ++e) {        // w2T[f][h] = mp_w2[h*F+f]
        const int idx = e * 256 + tid;   // float4 over f
        const int h = idx >> 4, ff4 = idx & 15;
        const float4 v = *(const float4*)(mp_w2 + h * F_ + ff4 * 4);
        s_w2T[(ff4 * 4 + 0) * HP + h] = (h16)v.x;
        s_w2T[(ff4 * 4 + 1) * HP + h] = (h16)v.y;
        s_w2T[(ff4 * 4 + 2) * HP + h] = (h16)v.z;
        s_w2T[(ff4 * 4 + 3) * HP + h] = (h16)v.w;
    }
    __syncthreads();   // (1) hidA/w2T/w1B/w2B/ri complete

    // ===== P2: vals(64x64) = sp(hid @ w2 + b2) via MFMA; write valsT f16 ===
    {
        f32x4 vacc[4];
        #pragma unroll
        for (int ft = 0; ft < 4; ++ft) vacc[ft] = (f32x4){0.f, 0.f, 0.f, 0.f};
        #pragma unroll
        for (int ks = 0; ks < 4; ++ks) {
            const h16x8 af = *(const h16x8*)&s_hidA[(wv * 16 + ln) * HP + ks * 32 + q * 8];
            #pragma unroll
            for (int ft = 0; ft < 4; ++ft) {
                const h16x8 bf = *(const h16x8*)&s_w2T[(ft * 16 + ln) * HP + ks * 32 + q * 8];
                vacc[ft] = __builtin_amdgcn_mfma_f32_16x16x32_f16(af, bf, vacc[ft], 0, 0, 0);
            }
        }
        // C layout: row m = wv*16+q*4+rr, col f = ft*16+ln -> valsT[f][m]
        #pragma unroll
        for (int ft = 0; ft < 4; ++ft) {
            const float b2v = mp_b2[ft * 16 + ln];
            const float vv[4] = {vacc[ft].x, vacc[ft].y, vacc[ft].z, vacc[ft].w};
            #pragma unroll
            for (int rr = 0; rr < 4; ++rr)
                s_valsT[(ft * 16 + ln) * MP + wv * 16 + q * 4 + rr] = (h16)sp(vv[rr] + b2v);
        }
    }
    __syncthreads();   // (2) valsT complete; hidA/w2T dead -> arena[0,33792) free

    // ===== concurrent epoch: c-MFMA (reads valsT) + fbT staging + x tile ===
    // c-MFMA: cT[f][k] = sum_m valsT[f][m] * W[m][k], W[m][k]=scale_k*cos(k*th_m)
    {
        f32x4 cacc = (f32x4){0.f, 0.f, 0.f, 0.f};
        #pragma unroll
        for (int cc = 0; cc < 2; ++cc) {
            const h16x8 af = *(const h16x8*)&s_valsT[(wv * 16 + ln) * MP + cc * 32 + q * 8];
            h16x8 bf;
            #pragma unroll
            for (int e = 0; e < 8; ++e) {
                const int m = cc * 32 + q * 8 + e;
                const float th = PI_F * ((float)m + 0.5f) / (float)M_;
                bf[e] = (h16)__cosf((float)ln * th);
            }
            cacc = __builtin_amdgcn_mfma_f32_16x16x32_f16(af, bf, cacc, 0, 0, 0);
        }
        if (ln < K_) {   // col = k = ln; row = q*4+rr -> f = wv*16+q*4+rr
            const float scale = ((ln == 0) ? 1.0f : 2.0f) / (float)M_;
            const float cv[4] = {cacc.x, cacc.y, cacc.z, cacc.w};
            #pragma unroll
            for (int rr = 0; rr < 4; ++rr)
                s_c[ln * F_ + wv * 16 + q * 4 + rr] = scale * cv[rr];
        }
    }
    // fbT from prefetched registers (f32 -> f16 transpose)
    #pragma unroll
    for (int jb = 0; jb < 8; ++jb) {
        const int j0 = jb * 32 + jp * 2;
        const float a0[4] = {pf0[jb].x, pf0[jb].y, pf0[jb].z, pf0[jb].w};
        const float a1[4] = {pf1[jb].x, pf1[jb].y, pf1[jb].z, pf1[jb].w};
        #pragma unroll
        for (int ff = 0; ff < 4; ++ff) {
            h16x2 pk; pk.x = (h16)a0[ff]; pk.y = (h16)a1[ff];
            *(h16x2*)&s_fbT[(f4 * 4 + ff) * LROW + j0] = pk;
        }
    }
    // x tile from prefetched coords
    {
        const float sc = 2.0f / DMAX;
        #pragma unroll
        for (int m = 0; m < 16; ++m) {
            const float dx = s_ri[m * 3 + 0] - xj;
            const float dy = s_ri[m * 3 + 1] - yj;
            const float dz = s_ri[m * 3 + 2] - zj;
            const float sq = fmaf(dx, dx, fmaf(dy, dy, dz * dz));
            const float d  = sq > 0.0f ? sqrtf(sq) : 0.0f;
            s_xs[m * LROW + tid] = (h16)(fmaf(d, sc, -1.0f));
        }
    }
    __syncthreads();   // (3) s_c / fbT / x complete

    // ===== fragments; wave wv owns j [wv*64, wv*64+64) =====================
    h16x8 bfrag[2][4];
    h16x8 x8[2];
    #pragma unroll
    for (int cc = 0; cc < 2; ++cc) {
        const int j0 = wv * 64 + cc * 32;
        x8[cc] = *(const h16x8*)&s_xs[ln * LROW + j0 + q * 8];
        #pragma unroll
        for (int ft = 0; ft < 4; ++ft)
            bfrag[cc][ft] = *(const h16x8*)&s_fbT[(ft * 16 + ln) * LROW + j0 + q * 8];
    }
    __syncthreads();   // (4) fbT reads done; arena becomes s_part

    h16x8 ones, twox[2], ta[2], tb[2];
    #pragma unroll
    for (int e = 0; e < 8; ++e) ones[e] = (h16)1.0f;
    #pragma unroll
    for (int cc = 0; cc < 2; ++cc) {
        twox[cc] = x8[cc] + x8[cc];
        ta[cc] = ones;       // T_0
        tb[cc] = x8[cc];     // T_1
    }

    f32x4 facc[4];
    #pragma unroll
    for (int ft = 0; ft < 4; ++ft) facc[ft] = (f32x4){0.f, 0.f, 0.f, 0.f};
    const f32x4 z4 = (f32x4){0.f, 0.f, 0.f, 0.f};

    for (int k = 0; k < K_; ++k) {
        f32x4 a2[4];
        #pragma unroll
        for (int ft = 0; ft < 4; ++ft) {
            a2[ft] = __builtin_amdgcn_mfma_f32_16x16x32_f16(ta[0], bfrag[0][ft], z4, 0, 0, 0);
            a2[ft] = __builtin_amdgcn_mfma_f32_16x16x32_f16(ta[1], bfrag[1][ft], a2[ft], 0, 0, 0);
        }
        #pragma unroll
        for (int ft = 0; ft < 4; ++ft) {
            const float ck = s_c[k * F_ + ft * 16 + ln];
            facc[ft].x = fmaf(ck, a2[ft].x, facc[ft].x);
            facc[ft].y = fmaf(ck, a2[ft].y, facc[ft].y);
            facc[ft].z = fmaf(ck, a2[ft].z, facc[ft].z);
            facc[ft].w = fmaf(ck, a2[ft].w, facc[ft].w);
        }
        #pragma unroll
        for (int cc = 0; cc < 2; ++cc) {
            const h16x8 tn = twox[cc] * tb[cc] - ta[cc];
            ta[cc] = tb[cc];
            tb[cc] = tn;
        }
    }

    // ---- cross-wave C partials (layout col=ln, row=q*4+rr) ----
    #pragma unroll
    for (int ft = 0; ft < 4; ++ft) {
        const float v[4] = {facc[ft].x, facc[ft].y, facc[ft].z, facc[ft].w};
        #pragma unroll
        for (int rr = 0; rr < 4; ++rr)
            s_part[(wv * 16 + q * 4 + rr) * 68 + ft * 16 + ln] = v[rr];
    }
    __syncthreads();   // (5)

    // ---- reduce 4 waves -> f_bar (f16, A-layout rows i) ----
    {
        const int f  = tid & 63;
        const int ig = tid >> 6;
        #pragma unroll
        for (int p = 0; p < 4; ++p) {
            const int i = ig * 4 + p;
            const float s = s_part[(0 * 16 + i) * 68 + f] + s_part[(1 * 16 + i) * 68 + f]
                          + s_part[(2 * 16 + i) * 68 + f] + s_part[(3 * 16 + i) * 68 + f];
            s_fbA[i * FBP + f] = (h16)sp(s);
        }
    }
    __syncthreads();   // (6)

    // ===== tail 1: h2(16x128) = sp(fbar @ pc_w1 + b1), wave wv: n-tiles 2wv,2wv+1
    {
        #pragma unroll
        for (int t2 = 0; t2 < 2; ++t2) {
            const int nt = wv * 2 + t2;
            f32x4 hacc = (f32x4){0.f, 0.f, 0.f, 0.f};
            #pragma unroll
            for (int ks = 0; ks < 2; ++ks) {
                const h16x8 af = *(const h16x8*)&s_fbA[ln * FBP + ks * 32 + q * 8];
                const h16x8 bf = *(const h16x8*)&s_w1B[(nt * 16 + ln) * FBP + ks * 32 + q * 8];
                hacc = __builtin_amdgcn_mfma_f32_16x16x32_f16(af, bf, hacc, 0, 0, 0);
            }
            const float b1v = pc_b1[nt * 16 + ln];
            const float hv[4] = {hacc.x, hacc.y, hacc.z, hacc.w};
            #pragma unroll
            for (int rr = 0; rr < 4; ++rr)
                s_h2A[(q * 4 + rr) * HP + nt * 16 + ln] = (h16)sp(hv[rr] + b1v);
        }
    }
    __syncthreads();   // (7)

    // ===== tail 2: out(16x16) = sp(h2 @ pc_w2 + b2); waves duplicate, wv0 writes
    {
        f32x4 oacc = (f32x4){0.f, 0.f, 0.f, 0.f};
        #pragma unroll
        for (int ks = 0; ks < 4; ++ks) {
            const h16x8 af = *(const h16x8*)&s_h2A[ln * HP + ks * 32 + q * 8];
            const h16x8 bf = *(const h16x8*)&s_w2B[ln * HP + ks * 32 + q * 8];
            oacc = __builtin_amdgcn_mfma_f32_16x16x32_f16(af, bf, oacc, 0, 0, 0);
        }
        if (wv == 0) {
            const float b2v = pc_b2[ln];
            const float ov[4] = {oacc.x, oacc.y, oacc.z, oacc.w};
            #pragma unroll
            for (int rr = 0; rr < 4; ++rr)
                out[((size_t)(b * N_ + i0 + q * 4 + rr)) * FP_ + ln] = sp(ov[rr] + b2v);
        }
    }
}

extern "C" void kernel_launch(void* const* d_in, const int* in_sizes, int n_in,
                              void* d_out, int out_size, void* d_ws, size_t ws_size,
                              hipStream_t stream) {
    const float* r_batch = (const float*)d_in[0];
    const float* f_batch = (const float*)d_in[1];
    const float* mp_w1   = (const float*)d_in[2];
    const float* mp_b1   = (const float*)d_in[3];
    const float* mp_w2   = (const float*)d_in[4];
    const float* mp_b2   = (const float*)d_in[5];
    const float* pc_w1   = (const float*)d_in[6];
    const float* pc_b1   = (const float*)d_in[7];
    const float* pc_w2   = (const float*)d_in[8];
    const float* pc_b2   = (const float*)d_in[9];
    float* out = (float*)d_out;

    pp_fused<<<B_ * (N_ / 16), 256, 0, stream>>>(
        r_batch, f_batch, mp_w1, mp_b1, mp_w2, mp_b2,
        pc_w1, pc_b1, pc_w2, pc_b2, out);
}

// Round 14
// 81.551 us; speedup vs baseline: 1.6957x; 1.0479x over previous
//
#include <hip/hip_runtime.h>
#include <math.h>

#define B_   16
#define N_   256
#define F_   64
#define FP_  16
#define H_   128
#define K_   14                    // Chebyshev terms
#define M_   64                    // Gauss-Chebyshev fit nodes
#define DMAX 1.7320508075688772f   // sqrt(3): r in [0,1]^3
#define PI_F 3.14159265358979323846f
#define LROW 264                   // fbT / x row stride (h16), 256-col rows
#define HP   136                   // 128-col h16 row stride (pad 8)
#define FBP  72                    // 64-col h16 row stride (pad 8)
#define MP   72                    // valsT row stride (h16), 64 m-cols (pad 8)

typedef _Float16 h16;
typedef __attribute__((ext_vector_type(2))) _Float16 h16x2;
typedef __attribute__((ext_vector_type(4))) _Float16 h16x4;
typedef __attribute__((ext_vector_type(8))) _Float16 h16x8;
typedef __attribute__((ext_vector_type(4))) float    f32x4;

__device__ __forceinline__ float sp(float x) {
    // softplus via native v_exp/v_log: 1+e^{-|x|} in (1,2], no cancellation
    return fmaxf(x, 0.0f) + __logf(1.0f + __expf(-fabsf(x)));
}

// ONE dispatch, 512-thread blocks (8 waves = 2 waves/SIMD for latency hiding).
// Per block (16-row i-tile): MFMA Chebyshev fit of the per-pair MLP (waves 0-3)
// concurrent with fbT/x staging (waves 4-7), then 8-wave MFMA main loop
// (f_bar = sum_k c_k T_k(X) @ fb), then MFMA pointwise-MLP tail.
// grid = B_*(N_/16) = 256 blocks.
__global__ __launch_bounds__(512) void pp_fused(
        const float* __restrict__ r,     const float* __restrict__ fb,
        const float* __restrict__ mp_w1, const float* __restrict__ mp_b1,
        const float* __restrict__ mp_w2, const float* __restrict__ mp_b2,
        const float* __restrict__ pc_w1, const float* __restrict__ pc_b1,
        const float* __restrict__ pc_w2, const float* __restrict__ pc_b2,
        float* __restrict__ out) {
    const int tid  = threadIdx.x;
    const int b    = blockIdx.x >> 4;
    const int i0   = (blockIdx.x & 15) << 4;
    const int wv   = tid >> 6;           // wave 0..7
    const int lane = tid & 63;
    const int ln   = lane & 15;          // A-row m / B-col n
    const int q    = lane >> 4;          // quad -> k-chunk

    // static buffers (no aliasing except s_part over hidA+w2T, dead by then)
    __shared__ __align__(16) h16 s_hidA[64 * HP];     // 17408 B  [m][h]
    __shared__ __align__(16) h16 s_w2T [F_ * HP];     // 17408 B  [f][h]
    __shared__ __align__(16) h16 s_valsT[F_ * MP];    //  9216 B  [f][m]
    __shared__ __align__(16) h16 s_fbT [F_ * LROW];   // 33792 B  [f][j]
    __shared__ __align__(16) h16 s_xs  [16 * LROW];   //  8448 B  [i][j]
    __shared__ float s_c  [K_ * F_];                  //  3584 B
    __shared__ h16   s_w1B[H_ * FBP];                 // 18432 B  [h][f]
    __shared__ h16   s_w2B[FP_ * HP];                 //  4352 B  [p][h]
    __shared__ h16   s_fbA[16 * FBP];                 //  2304 B  [i][f]
    __shared__ h16   s_h2A[16 * HP];                  //  4352 B  [i][h]
    __shared__ float s_ri [48];
    float* s_part = (float*)s_hidA;      // [8][16][68] = 34816 B over hidA+w2T

    // ===== prefetch (waves 4-7): fb tile + own r coords into registers =====
    const int st = tid & 255;            // staging-thread id within waves 4-7
    const int f4 = st & 15;
    const int jp = st >> 4;
    float4 pf0[8], pf1[8];
    float xj = 0.f, yj = 0.f, zj = 0.f;
    if (wv >= 4) {
        const float* fbb = fb + (size_t)b * N_ * F_;
        #pragma unroll
        for (int jb = 0; jb < 8; ++jb) {
            const int j0 = jb * 32 + jp * 2;
            pf0[jb] = *(const float4*)(fbb + (size_t)j0 * F_ + f4 * 4);
            pf1[jb] = *(const float4*)(fbb + (size_t)(j0 + 1) * F_ + f4 * 4);
        }
        xj = r[((size_t)b * N_ + st) * 3 + 0];
        yj = r[((size_t)b * N_ + st) * 3 + 1];
        zj = r[((size_t)b * N_ + st) * 3 + 2];
    }

    // ===== epoch A: stage weights (split over 512 threads) ================
    if (tid < 48) s_ri[tid] = r[((size_t)b * N_ + i0) * 3 + tid];
    #pragma unroll
    for (int e = 0; e < 4; ++e) {        // w1B[h][f] = pc_w1[f*H+h]
        const int idx = e * 512 + tid;   // float4 over h
        const int f = idx >> 5, h4 = idx & 31;
        const float4 v = *(const float4*)(pc_w1 + f * H_ + h4 * 4);
        s_w1B[(h4 * 4 + 0) * FBP + f] = (h16)v.x;
        s_w1B[(h4 * 4 + 1) * FBP + f] = (h16)v.y;
        s_w1B[(h4 * 4 + 2) * FBP + f] = (h16)v.z;
        s_w1B[(h4 * 4 + 3) * FBP + f] = (h16)v.w;
    }
    #pragma unroll
    for (int e = 0; e < 4; ++e) {        // w2B[p][h] = pc_w2[h*FP+p]
        const int idx = e * 512 + tid;
        const int h = idx >> 4, p = idx & 15;
        s_w2B[p * HP + h] = (h16)pc_w2[idx];
    }
    #pragma unroll
    for (int e = 0; e < 4; ++e) {        // w2T[f][h] = mp_w2[h*F+f]
        const int idx = e * 512 + tid;   // float4 over f
        const int h = idx >> 4, ff4 = idx & 15;
        const float4 v = *(const float4*)(mp_w2 + h * F_ + ff4 * 4);
        s_w2T[(ff4 * 4 + 0) * HP + h] = (h16)v.x;
        s_w2T[(ff4 * 4 + 1) * HP + h] = (h16)v.y;
        s_w2T[(ff4 * 4 + 2) * HP + h] = (h16)v.z;
        s_w2T[(ff4 * 4 + 3) * HP + h] = (h16)v.w;
    }
    {   // P1: hidA[m][h] = sp(d_m * w1[h] + b1[h]); 8 threads per node m
        const int m  = tid >> 3;
        const int h0 = (tid & 7) * 16;
        const float th = PI_F * ((float)m + 0.5f) / (float)M_;
        const float d  = (__cosf(th) + 1.0f) * 0.5f * DMAX;
        #pragma unroll
        for (int hq = 0; hq < 4; ++hq) {
            const float4 w  = *(const float4*)(mp_w1 + h0 + hq * 4);
            const float4 bb = *(const float4*)(mp_b1 + h0 + hq * 4);
            h16x4 hv;
            hv.x = (h16)sp(fmaf(d, w.x, bb.x));
            hv.y = (h16)sp(fmaf(d, w.y, bb.y));
            hv.z = (h16)sp(fmaf(d, w.z, bb.z));
            hv.w = (h16)sp(fmaf(d, w.w, bb.w));
            *(h16x4*)&s_hidA[m * HP + h0 + hq * 4] = hv;
        }
    }
    __syncthreads();   // (1)

    // ===== epoch B: waves 0-3: P2 vals MFMA | waves 4-7: fbT transpose =====
    if (wv < 4) {
        f32x4 vacc[4];
        #pragma unroll
        for (int ft = 0; ft < 4; ++ft) vacc[ft] = (f32x4){0.f, 0.f, 0.f, 0.f};
        #pragma unroll
        for (int ks = 0; ks < 4; ++ks) {
            const h16x8 af = *(const h16x8*)&s_hidA[(wv * 16 + ln) * HP + ks * 32 + q * 8];
            #pragma unroll
            for (int ft = 0; ft < 4; ++ft) {
                const h16x8 bf = *(const h16x8*)&s_w2T[(ft * 16 + ln) * HP + ks * 32 + q * 8];
                vacc[ft] = __builtin_amdgcn_mfma_f32_16x16x32_f16(af, bf, vacc[ft], 0, 0, 0);
            }
        }
        // C layout: row m = wv*16+q*4+rr, col f = ft*16+ln -> valsT[f][m]
        #pragma unroll
        for (int ft = 0; ft < 4; ++ft) {
            const float b2v = mp_b2[ft * 16 + ln];
            const float vv[4] = {vacc[ft].x, vacc[ft].y, vacc[ft].z, vacc[ft].w};
            #pragma unroll
            for (int rr = 0; rr < 4; ++rr)
                s_valsT[(ft * 16 + ln) * MP + wv * 16 + q * 4 + rr] = (h16)sp(vv[rr] + b2v);
        }
    } else {
        #pragma unroll
        for (int jb = 0; jb < 8; ++jb) {
            const int j0 = jb * 32 + jp * 2;
            const float a0[4] = {pf0[jb].x, pf0[jb].y, pf0[jb].z, pf0[jb].w};
            const float a1[4] = {pf1[jb].x, pf1[jb].y, pf1[jb].z, pf1[jb].w};
            #pragma unroll
            for (int ff = 0; ff < 4; ++ff) {
                h16x2 pk; pk.x = (h16)a0[ff]; pk.y = (h16)a1[ff];
                *(h16x2*)&s_fbT[(f4 * 4 + ff) * LROW + j0] = pk;
            }
        }
    }
    __syncthreads();   // (2)

    // ===== epoch C: waves 0-3: c-MFMA -> s_c | waves 4-7: x tile ===========
    if (wv < 4) {
        // cT[f][k] = sum_m valsT[f][m] * W[m][k], W[m][k]=scale_k*cos(k*th_m)
        f32x4 cacc = (f32x4){0.f, 0.f, 0.f, 0.f};
        #pragma unroll
        for (int cc = 0; cc < 2; ++cc) {
            const h16x8 af = *(const h16x8*)&s_valsT[(wv * 16 + ln) * MP + cc * 32 + q * 8];
            h16x8 bf;
            #pragma unroll
            for (int e = 0; e < 8; ++e) {
                const int m = cc * 32 + q * 8 + e;
                const float th = PI_F * ((float)m + 0.5f) / (float)M_;
                bf[e] = (h16)__cosf((float)ln * th);
            }
            cacc = __builtin_amdgcn_mfma_f32_16x16x32_f16(af, bf, cacc, 0, 0, 0);
        }
        if (ln < K_) {   // col = k = ln; row f = wv*16+q*4+rr
            const float scale = ((ln == 0) ? 1.0f : 2.0f) / (float)M_;
            const float cv[4] = {cacc.x, cacc.y, cacc.z, cacc.w};
            #pragma unroll
            for (int rr = 0; rr < 4; ++rr)
                s_c[ln * F_ + wv * 16 + q * 4 + rr] = scale * cv[rr];
        }
    } else {
        const float sc = 2.0f / DMAX;
        #pragma unroll
        for (int m = 0; m < 16; ++m) {
            const float dx = s_ri[m * 3 + 0] - xj;
            const float dy = s_ri[m * 3 + 1] - yj;
            const float dz = s_ri[m * 3 + 2] - zj;
            const float sq = fmaf(dx, dx, fmaf(dy, dy, dz * dz));
            const float d  = sq > 0.0f ? sqrtf(sq) : 0.0f;
            s_xs[m * LROW + st] = (h16)(fmaf(d, sc, -1.0f));
        }
    }
    __syncthreads();   // (3)

    // ===== main: 8 waves, wave wv owns j [wv*32, wv*32+32) =================
    const int j0 = wv * 32 + q * 8;
    const h16x8 x8 = *(const h16x8*)&s_xs[ln * LROW + j0];
    h16x8 bfrag[4];
    #pragma unroll
    for (int ft = 0; ft < 4; ++ft)
        bfrag[ft] = *(const h16x8*)&s_fbT[(ft * 16 + ln) * LROW + j0];

    h16x8 ones, twox, ta, tb;
    #pragma unroll
    for (int e = 0; e < 8; ++e) ones[e] = (h16)1.0f;
    twox = x8 + x8;
    ta = ones;       // T_0
    tb = x8;         // T_1

    f32x4 facc[4];
    #pragma unroll
    for (int ft = 0; ft < 4; ++ft) facc[ft] = (f32x4){0.f, 0.f, 0.f, 0.f};
    const f32x4 z4 = (f32x4){0.f, 0.f, 0.f, 0.f};

    for (int k = 0; k < K_; ++k) {
        #pragma unroll
        for (int ft = 0; ft < 4; ++ft) {
            const f32x4 a2 = __builtin_amdgcn_mfma_f32_16x16x32_f16(ta, bfrag[ft], z4, 0, 0, 0);
            const float ck = s_c[k * F_ + ft * 16 + ln];
            facc[ft].x = fmaf(ck, a2.x, facc[ft].x);
            facc[ft].y = fmaf(ck, a2.y, facc[ft].y);
            facc[ft].z = fmaf(ck, a2.z, facc[ft].z);
            facc[ft].w = fmaf(ck, a2.w, facc[ft].w);
        }
        const h16x8 tn = twox * tb - ta;
        ta = tb;
        tb = tn;
    }

    // ---- per-wave C partials (hidA/w2T dead; s_part aliases them) ----
    #pragma unroll
    for (int ft = 0; ft < 4; ++ft) {
        const float v[4] = {facc[ft].x, facc[ft].y, facc[ft].z, facc[ft].w};
        #pragma unroll
        for (int rr = 0; rr < 4; ++rr)
            s_part[(wv * 16 + q * 4 + rr) * 68 + ft * 16 + ln] = v[rr];
    }
    __syncthreads();   // (4)

    // ---- reduce 8 waves -> f_bar (f16, A-layout rows i); 2 items/thread ----
    #pragma unroll
    for (int e = 0; e < 2; ++e) {
        const int item = e * 512 + tid;
        const int i = item >> 6, f = item & 63;
        float s = 0.0f;
        #pragma unroll
        for (int g = 0; g < 8; ++g)
            s += s_part[(g * 16 + i) * 68 + f];
        s_fbA[i * FBP + f] = (h16)sp(s);
    }
    __syncthreads();   // (5)

    // ===== tail 1: h2(16x128) = sp(fbar @ pc_w1 + b1); wave wv: n-tile wv ===
    {
        const int nt = wv;
        f32x4 hacc = (f32x4){0.f, 0.f, 0.f, 0.f};
        #pragma unroll
        for (int ks = 0; ks < 2; ++ks) {
            const h16x8 af = *(const h16x8*)&s_fbA[ln * FBP + ks * 32 + q * 8];
            const h16x8 bf = *(const h16x8*)&s_w1B[(nt * 16 + ln) * FBP + ks * 32 + q * 8];
            hacc = __builtin_amdgcn_mfma_f32_16x16x32_f16(af, bf, hacc, 0, 0, 0);
        }
        const float b1v = pc_b1[nt * 16 + ln];
        const float hv[4] = {hacc.x, hacc.y, hacc.z, hacc.w};
        #pragma unroll
        for (int rr = 0; rr < 4; ++rr)
            s_h2A[(q * 4 + rr) * HP + nt * 16 + ln] = (h16)sp(hv[rr] + b1v);
    }
    __syncthreads();   // (6)

    // ===== tail 2: out(16x16) = sp(h2 @ pc_w2 + b2); wave 0 writes =========
    {
        f32x4 oacc = (f32x4){0.f, 0.f, 0.f, 0.f};
        #pragma unroll
        for (int ks = 0; ks < 4; ++ks) {
            const h16x8 af = *(const h16x8*)&s_h2A[ln * HP + ks * 32 + q * 8];
            const h16x8 bf = *(const h16x8*)&s_w2B[ln * HP + ks * 32 + q * 8];
            oacc = __builtin_amdgcn_mfma_f32_16x16x32_f16(af, bf, oacc, 0, 0, 0);
        }
        if (wv == 0) {
            const float b2v = pc_b2[ln];
            const float ov[4] = {oacc.x, oacc.y, oacc.z, oacc.w};
            #pragma unroll
            for (int rr = 0; rr < 4; ++rr)
                out[((size_t)(b * N_ + i0 + q * 4 + rr)) * FP_ + ln] = sp(ov[rr] + b2v);
        }
    }
}

extern "C" void kernel_launch(void* const* d_in, const int* in_sizes, int n_in,
                              void* d_out, int out_size, void* d_ws, size_t ws_size,
                              hipStream_t stream) {
    const float* r_batch = (const float*)d_in[0];
    const float* f_batch = (const float*)d_in[1];
    const float* mp_w1   = (const float*)d_in[2];
    const float* mp_b1   = (const float*)d_in[3];
    const float* mp_w2   = (const float*)d_in[4];
    const float* mp_b2   = (const float*)d_in[5];
    const float* pc_w1   = (const float*)d_in[6];
    const float* pc_b1   = (const float*)d_in[7];
    const float* pc_w2   = (const float*)d_in[8];
    const float* pc_b2   = (const float*)d_in[9];
    float* out = (float*)d_out;

    pp_fused<<<B_ * (N_ / 16), 512, 0, stream>>>(
        r_batch, f_batch, mp_w1, mp_b1, mp_w2, mp_b2,
        pc_w1, pc_b1, pc_w2, pc_b2, out);
}

// Round 15
// 80.531 us; speedup vs baseline: 1.7172x; 1.0127x over previous
//
#include <hip/hip_runtime.h>
#include <math.h>

#define B_   16
#define N_   256
#define F_   64
#define FP_  16
#define H_   128
#define K_   14                    // Chebyshev terms
#define M_   64                    // Gauss-Chebyshev fit nodes
#define DMAX 1.7320508075688772f   // sqrt(3): r in [0,1]^3
#define PI_F 3.14159265358979323846f
#define LROW 264                   // fbT / x row stride (h16), 256-col rows
#define HP   136                   // 128-col h16 row stride (pad 8)
#define FBP  72                    // 64-col h16 row stride (pad 8)
#define MP   72                    // valsT row stride (h16), 64 m-cols (pad 8)

typedef _Float16 h16;
typedef __attribute__((ext_vector_type(2))) _Float16 h16x2;
typedef __attribute__((ext_vector_type(4))) _Float16 h16x4;
typedef __attribute__((ext_vector_type(8))) _Float16 h16x8;
typedef __attribute__((ext_vector_type(4))) float    f32x4;

__device__ __forceinline__ float sp(float x) {
    // softplus via native v_exp/v_log: 1+e^{-|x|} in (1,2], no cancellation
    return fmaxf(x, 0.0f) + __logf(1.0f + __expf(-fabsf(x)));
}

// ONE dispatch, 1024-thread blocks (16 waves = 4 waves/SIMD latency hiding).
// Per block (16-row i-tile): MFMA Chebyshev fit of the per-pair MLP (waves 0-7)
// concurrent with fbT/x staging (waves 8-15), then 16-wave MFMA main loop
// (f_bar = sum_k c_k T_k(X) @ fb), then MFMA pointwise-MLP tail.
// grid = B_*(N_/16) = 256 blocks.
__global__ __launch_bounds__(1024) void pp_fused(
        const float* __restrict__ r,     const float* __restrict__ fb,
        const float* __restrict__ mp_w1, const float* __restrict__ mp_b1,
        const float* __restrict__ mp_w2, const float* __restrict__ mp_b2,
        const float* __restrict__ pc_w1, const float* __restrict__ pc_b1,
        const float* __restrict__ pc_w2, const float* __restrict__ pc_b2,
        float* __restrict__ out) {
    const int tid  = threadIdx.x;
    const int b    = blockIdx.x >> 4;
    const int i0   = (blockIdx.x & 15) << 4;
    const int wv   = tid >> 6;           // wave 0..15
    const int lane = tid & 63;
    const int ln   = lane & 15;          // A-row m / B-col n
    const int q    = lane >> 4;          // quad -> k-chunk

    // static buffers (no aliasing except s_part over hidA+w2T, dead by then)
    __shared__ __align__(16) h16 s_hidA[64 * HP];     // 17408 B  [m][h]
    __shared__ __align__(16) h16 s_w2T [F_ * HP];     // 17408 B  [f][h]
    __shared__ __align__(16) h16 s_valsT[F_ * MP];    //  9216 B  [f][m]
    __shared__ __align__(16) h16 s_fbT [F_ * LROW];   // 33792 B  [f][j]
    __shared__ __align__(16) h16 s_xs  [16 * LROW];   //  8448 B  [i][j]
    __shared__ float s_c  [K_ * F_];                  //  3584 B
    __shared__ h16   s_w1B[H_ * FBP];                 // 18432 B  [h][f]
    __shared__ h16   s_w2B[FP_ * HP];                 //  4352 B  [p][h]
    __shared__ h16   s_fbA[16 * FBP];                 //  2304 B  [i][f]
    __shared__ h16   s_h2A[16 * HP];                  //  4352 B  [i][h]
    __shared__ float s_ri [48];
    float* s_part = (float*)s_hidA;      // [8][16][68] = 34816 B over hidA+w2T

    // ===== prefetch (waves 8-15): fb tile + own r coords into registers ====
    const int st = tid & 511;            // staging-thread id within waves 8-15
    const int f4 = st & 15;
    const int jp = st >> 4;              // 0..31
    float4 pf0[4], pf1[4];
    float xj = 0.f, yj = 0.f, zj = 0.f;
    if (wv >= 8) {
        const float* fbb = fb + (size_t)b * N_ * F_;
        #pragma unroll
        for (int jb = 0; jb < 4; ++jb) {
            const int j0 = jb * 64 + jp * 2;
            pf0[jb] = *(const float4*)(fbb + (size_t)j0 * F_ + f4 * 4);
            pf1[jb] = *(const float4*)(fbb + (size_t)(j0 + 1) * F_ + f4 * 4);
        }
        const int lj = st & 255;
        xj = r[((size_t)b * N_ + lj) * 3 + 0];
        yj = r[((size_t)b * N_ + lj) * 3 + 1];
        zj = r[((size_t)b * N_ + lj) * 3 + 2];
    }

    // ===== epoch A: stage weights (split over 1024 threads) ================
    if (tid < 48) s_ri[tid] = r[((size_t)b * N_ + i0) * 3 + tid];
    #pragma unroll
    for (int e = 0; e < 2; ++e) {        // w1B[h][f] = pc_w1[f*H+h]
        const int idx = e * 1024 + tid;  // float4 over h
        const int f = idx >> 5, h4 = idx & 31;
        const float4 v = *(const float4*)(pc_w1 + f * H_ + h4 * 4);
        s_w1B[(h4 * 4 + 0) * FBP + f] = (h16)v.x;
        s_w1B[(h4 * 4 + 1) * FBP + f] = (h16)v.y;
        s_w1B[(h4 * 4 + 2) * FBP + f] = (h16)v.z;
        s_w1B[(h4 * 4 + 3) * FBP + f] = (h16)v.w;
    }
    #pragma unroll
    for (int e = 0; e < 2; ++e) {        // w2B[p][h] = pc_w2[h*FP+p]
        const int idx = e * 1024 + tid;
        const int h = idx >> 4, p = idx & 15;
        s_w2B[p * HP + h] = (h16)pc_w2[idx];
    }
    #pragma unroll
    for (int e = 0; e < 2; ++e) {        // w2T[f][h] = mp_w2[h*F+f]
        const int idx = e * 1024 + tid;  // float4 over f
        const int h = idx >> 4, ff4 = idx & 15;
        const float4 v = *(const float4*)(mp_w2 + h * F_ + ff4 * 4);
        s_w2T[(ff4 * 4 + 0) * HP + h] = (h16)v.x;
        s_w2T[(ff4 * 4 + 1) * HP + h] = (h16)v.y;
        s_w2T[(ff4 * 4 + 2) * HP + h] = (h16)v.z;
        s_w2T[(ff4 * 4 + 3) * HP + h] = (h16)v.w;
    }
    {   // P1: hidA[m][h] = sp(d_m * w1[h] + b1[h]); 16 threads per node m
        const int m  = tid >> 4;
        const int h0 = (tid & 15) * 8;
        const float th = PI_F * ((float)m + 0.5f) / (float)M_;
        const float d  = (__cosf(th) + 1.0f) * 0.5f * DMAX;
        #pragma unroll
        for (int hq = 0; hq < 2; ++hq) {
            const float4 w  = *(const float4*)(mp_w1 + h0 + hq * 4);
            const float4 bb = *(const float4*)(mp_b1 + h0 + hq * 4);
            h16x4 hv;
            hv.x = (h16)sp(fmaf(d, w.x, bb.x));
            hv.y = (h16)sp(fmaf(d, w.y, bb.y));
            hv.z = (h16)sp(fmaf(d, w.z, bb.z));
            hv.w = (h16)sp(fmaf(d, w.w, bb.w));
            *(h16x4*)&s_hidA[m * HP + h0 + hq * 4] = hv;
        }
    }
    __syncthreads();   // (1)

    // ===== epoch B: waves 0-7: P2 vals MFMA | waves 8-15: fbT transpose ====
    if (wv < 8) {
        const int mt = wv & 3, fg = wv >> 2;     // m-tile, f-pair
        f32x4 vacc[2];
        #pragma unroll
        for (int t = 0; t < 2; ++t) vacc[t] = (f32x4){0.f, 0.f, 0.f, 0.f};
        #pragma unroll
        for (int ks = 0; ks < 4; ++ks) {
            const h16x8 af = *(const h16x8*)&s_hidA[(mt * 16 + ln) * HP + ks * 32 + q * 8];
            #pragma unroll
            for (int t = 0; t < 2; ++t) {
                const int ft = fg * 2 + t;
                const h16x8 bf = *(const h16x8*)&s_w2T[(ft * 16 + ln) * HP + ks * 32 + q * 8];
                vacc[t] = __builtin_amdgcn_mfma_f32_16x16x32_f16(af, bf, vacc[t], 0, 0, 0);
            }
        }
        // C layout: row m = mt*16+q*4+rr, col f = ft*16+ln -> valsT[f][m]
        #pragma unroll
        for (int t = 0; t < 2; ++t) {
            const int ft = fg * 2 + t;
            const float b2v = mp_b2[ft * 16 + ln];
            const float vv[4] = {vacc[t].x, vacc[t].y, vacc[t].z, vacc[t].w};
            #pragma unroll
            for (int rr = 0; rr < 4; ++rr)
                s_valsT[(ft * 16 + ln) * MP + mt * 16 + q * 4 + rr] = (h16)sp(vv[rr] + b2v);
        }
    } else {
        #pragma unroll
        for (int jb = 0; jb < 4; ++jb) {
            const int j0 = jb * 64 + jp * 2;
            const float a0[4] = {pf0[jb].x, pf0[jb].y, pf0[jb].z, pf0[jb].w};
            const float a1[4] = {pf1[jb].x, pf1[jb].y, pf1[jb].z, pf1[jb].w};
            #pragma unroll
            for (int ff = 0; ff < 4; ++ff) {
                h16x2 pk; pk.x = (h16)a0[ff]; pk.y = (h16)a1[ff];
                *(h16x2*)&s_fbT[(f4 * 4 + ff) * LROW + j0] = pk;
            }
        }
    }
    __syncthreads();   // (2)

    // ===== epoch C: waves 0-3: c-MFMA -> s_c | waves 8-15: x tile ==========
    if (wv < 4) {
        // cT[f][k] = sum_m valsT[f][m] * W[m][k], W[m][k]=scale_k*cos(k*th_m)
        f32x4 cacc = (f32x4){0.f, 0.f, 0.f, 0.f};
        #pragma unroll
        for (int cc = 0; cc < 2; ++cc) {
            const h16x8 af = *(const h16x8*)&s_valsT[(wv * 16 + ln) * MP + cc * 32 + q * 8];
            h16x8 bf;
            #pragma unroll
            for (int e = 0; e < 8; ++e) {
                const int m = cc * 32 + q * 8 + e;
                const float th = PI_F * ((float)m + 0.5f) / (float)M_;
                bf[e] = (h16)__cosf((float)ln * th);
            }
            cacc = __builtin_amdgcn_mfma_f32_16x16x32_f16(af, bf, cacc, 0, 0, 0);
        }
        if (ln < K_) {   // col = k = ln; row f = wv*16+q*4+rr
            const float scale = ((ln == 0) ? 1.0f : 2.0f) / (float)M_;
            const float cv[4] = {cacc.x, cacc.y, cacc.z, cacc.w};
            #pragma unroll
            for (int rr = 0; rr < 4; ++rr)
                s_c[ln * F_ + wv * 16 + q * 4 + rr] = scale * cv[rr];
        }
    } else if (wv >= 8) {
        const int lj   = st & 255;
        const int half = st >> 8;
        const float sc = 2.0f / DMAX;
        #pragma unroll
        for (int mm = 0; mm < 8; ++mm) {
            const int m = half * 8 + mm;
            const float dx = s_ri[m * 3 + 0] - xj;
            const float dy = s_ri[m * 3 + 1] - yj;
            const float dz = s_ri[m * 3 + 2] - zj;
            const float sq = fmaf(dx, dx, fmaf(dy, dy, dz * dz));
            const float d  = sq > 0.0f ? sqrtf(sq) : 0.0f;
            s_xs[m * LROW + lj] = (h16)(fmaf(d, sc, -1.0f));
        }
    }
    __syncthreads();   // (3)

    // ===== main: 16 waves; wave = (jw 0..7, fg 0..1) =======================
    const int jw = wv & 7, fg = wv >> 3;
    const int j0 = jw * 32 + q * 8;
    const h16x8 x8 = *(const h16x8*)&s_xs[ln * LROW + j0];
    h16x8 bfrag[2];
    #pragma unroll
    for (int t = 0; t < 2; ++t)
        bfrag[t] = *(const h16x8*)&s_fbT[((fg * 2 + t) * 16 + ln) * LROW + j0];

    h16x8 ones, twox, ta, tb;
    #pragma unroll
    for (int e = 0; e < 8; ++e) ones[e] = (h16)1.0f;
    twox = x8 + x8;
    ta = ones;       // T_0
    tb = x8;         // T_1

    f32x4 facc[2];
    #pragma unroll
    for (int t = 0; t < 2; ++t) facc[t] = (f32x4){0.f, 0.f, 0.f, 0.f};
    const f32x4 z4 = (f32x4){0.f, 0.f, 0.f, 0.f};

    for (int k = 0; k < K_; ++k) {
        #pragma unroll
        for (int t = 0; t < 2; ++t) {
            const f32x4 a2 = __builtin_amdgcn_mfma_f32_16x16x32_f16(ta, bfrag[t], z4, 0, 0, 0);
            const float ck = s_c[k * F_ + (fg * 2 + t) * 16 + ln];
            facc[t].x = fmaf(ck, a2.x, facc[t].x);
            facc[t].y = fmaf(ck, a2.y, facc[t].y);
            facc[t].z = fmaf(ck, a2.z, facc[t].z);
            facc[t].w = fmaf(ck, a2.w, facc[t].w);
        }
        const h16x8 tn = twox * tb - ta;
        ta = tb;
        tb = tn;
    }

    // ---- per-wave C partials (hidA/w2T dead; s_part aliases them) ----
    // row i = q*4+rr (within tile), j-group jw, col f = (fg*2+t)*16+ln
    #pragma unroll
    for (int t = 0; t < 2; ++t) {
        const float v[4] = {facc[t].x, facc[t].y, facc[t].z, facc[t].w};
        #pragma unroll
        for (int rr = 0; rr < 4; ++rr)
            s_part[(jw * 16 + q * 4 + rr) * 68 + (fg * 2 + t) * 16 + ln] = v[rr];
    }
    __syncthreads();   // (4)

    // ---- reduce 8 j-groups -> f_bar (f16, A-layout rows i); 1 item/thread --
    {
        const int i = tid >> 6, f = tid & 63;
        float s = 0.0f;
        #pragma unroll
        for (int g = 0; g < 8; ++g)
            s += s_part[(g * 16 + i) * 68 + f];
        s_fbA[i * FBP + f] = (h16)sp(s);
    }
    __syncthreads();   // (5)

    // ===== tail 1: h2(16x128) = sp(fbar @ pc_w1 + b1); waves 0-7: n-tile wv =
    if (wv < 8) {
        const int nt = wv;
        f32x4 hacc = (f32x4){0.f, 0.f, 0.f, 0.f};
        #pragma unroll
        for (int ks = 0; ks < 2; ++ks) {
            const h16x8 af = *(const h16x8*)&s_fbA[ln * FBP + ks * 32 + q * 8];
            const h16x8 bf = *(const h16x8*)&s_w1B[(nt * 16 + ln) * FBP + ks * 32 + q * 8];
            hacc = __builtin_amdgcn_mfma_f32_16x16x32_f16(af, bf, hacc, 0, 0, 0);
        }
        const float b1v = pc_b1[nt * 16 + ln];
        const float hv[4] = {hacc.x, hacc.y, hacc.z, hacc.w};
        #pragma unroll
        for (int rr = 0; rr < 4; ++rr)
            s_h2A[(q * 4 + rr) * HP + nt * 16 + ln] = (h16)sp(hv[rr] + b1v);
    }
    __syncthreads();   // (6)

    // ===== tail 2: out(16x16) = sp(h2 @ pc_w2 + b2); wave 0 only ===========
    if (wv == 0) {
        f32x4 oacc = (f32x4){0.f, 0.f, 0.f, 0.f};
        #pragma unroll
        for (int ks = 0; ks < 4; ++ks) {
            const h16x8 af = *(const h16x8*)&s_h2A[ln * HP + ks * 32 + q * 8];
            const h16x8 bf = *(const h16x8*)&s_w2B[ln * HP + ks * 32 + q * 8];
            oacc = __builtin_amdgcn_mfma_f32_16x16x32_f16(af, bf, oacc, 0, 0, 0);
        }
        const float b2v = pc_b2[ln];
        const float ov[4] = {oacc.x, oacc.y, oacc.z, oacc.w};
        #pragma unroll
        for (int rr = 0; rr < 4; ++rr)
            out[((size_t)(b * N_ + i0 + q * 4 + rr)) * FP_ + ln] = sp(ov[rr] + b2v);
    }
}

extern "C" void kernel_launch(void* const* d_in, const int* in_sizes, int n_in,
                              void* d_out, int out_size, void* d_ws, size_t ws_size,
                              hipStream_t stream) {
    const float* r_batch = (const float*)d_in[0];
    const float* f_batch = (const float*)d_in[1];
    const float* mp_w1   = (const float*)d_in[2];
    const float* mp_b1   = (const float*)d_in[3];
    const float* mp_w2   = (const float*)d_in[4];
    const float* mp_b2   = (const float*)d_in[5];
    const float* pc_w1   = (const float*)d_in[6];
    const float* pc_b1   = (const float*)d_in[7];
    const float* pc_w2   = (const float*)d_in[8];
    const float* pc_b2   = (const float*)d_in[9];
    float* out = (float*)d_out;

    pp_fused<<<B_ * (N_ / 16), 1024, 0, stream>>>(
        r_batch, f_batch, mp_w1, mp_b1, mp_w2, mp_b2,
        pc_w1, pc_b1, pc_w2, pc_b2, out);
}